// Round 7
// baseline (586.988 us; speedup 1.0000x reference)
//
#include <hip/hip_runtime.h>
#include <hip/hip_fp16.h>

#define DD 128
#define HH 15
#define BSHIFT 8                 // 256 nodes per bucket
#define BUCK (1 << BSHIFT)
#define NBUCK 391                // ceil(100000 / 256)
#define CAP 18432                // fixed bucket capacity: mean 16368 + 16 sigma
#define CHUNK 1042               // edges per partA block: ceil(6.4M/1042)=6143 = 3x2048 pipes
#define ABLK 256                 // partA block size (4 waves -> 8 blocks/CU resident)
#define EPT 5                    // ceil(CHUNK/ABLK)

// ---------------- init: absolute bucket cursors at fixed capacity ----------------

__global__ __launch_bounds__(512) void init_gcur(int* __restrict__ gcur) {
    int i = threadIdx.x;
    if (i < NBUCK) gcur[i] = i * CAP;
}

// ---------------- CSR build, phase A: LDS-staged bucket binning ----------------
// pack = row (17b) | local_col (8b) << 17. Fixed-capacity bucket regions in tmp.
// 256 threads, CHUNK=1042 -> 6143 blocks = 3 exactly-full residency rounds.

__global__ __launch_bounds__(256, 8) void partA(const int* __restrict__ row, const int* __restrict__ col,
                      int* __restrict__ gcur, unsigned* __restrict__ tmp, int E) {
    __shared__ int histo[NBUCK];
    __shared__ int hbase[NBUCK];
    __shared__ int hscan[NBUCK];
    __shared__ int wsum[4];
    __shared__ int s_total;
    __shared__ unsigned staged[CHUNK];
    __shared__ int saddr[CHUNK];
    int tid = threadIdx.x;
    int start = blockIdx.x * CHUNK;
    for (int i = tid; i < NBUCK; i += ABLK) histo[i] = 0;
    __syncthreads();
    unsigned pk[EPT]; unsigned short lp[EPT]; unsigned short bk[EPT];
    for (int k = 0; k < EPT; ++k) {
        int off = k * ABLK + tid;
        int e = start + off;
        bk[k] = 0xFFFF;
        if (off < CHUNK && e < E) {
            int cc = col[e];
            int b = cc >> BSHIFT;
            int rr = row[e];
            pk[k] = (unsigned)rr | ((unsigned)(cc & (BUCK - 1)) << 17);
            bk[k] = (unsigned short)b;
            lp[k] = (unsigned short)atomicAdd(&histo[b], 1);
        }
    }
    __syncthreads();
    // pair scan: thread t owns buckets 2t, 2t+1 (196 pairs cover 391)
    int lane = tid & 63, wv = tid >> 6;
    int i0 = 2 * tid, i1 = 2 * tid + 1;
    int h0 = (i0 < NBUCK) ? histo[i0] : 0;
    int h1 = (i1 < NBUCK) ? histo[i1] : 0;
    int v = h0 + h1;
    int s = v;
#pragma unroll
    for (int off = 1; off < 64; off <<= 1) {
        int u = __shfl_up(s, off, 64);
        if (lane >= off) s += u;
    }
    if (lane == 63) wsum[wv] = s;
    __syncthreads();
    if (tid == 0) {
        int r = 0;
        for (int i = 0; i < 4; ++i) { int u = wsum[i]; wsum[i] = r; r += u; }
        s_total = r;
    }
    __syncthreads();
    int excl = s + wsum[wv] - v;
    if (i0 < NBUCK) {
        hscan[i0] = excl;
        if (h0 > 0) hbase[i0] = atomicAdd(&gcur[i0], h0);
    }
    if (i1 < NBUCK) {
        hscan[i1] = excl + h0;
        if (h1 > 0) hbase[i1] = atomicAdd(&gcur[i1], h1);
    }
    __syncthreads();
    for (int k = 0; k < EPT; ++k) {
        if (bk[k] != 0xFFFF) {
            int b = bk[k];
            int slot = hscan[b] + lp[k];
            saddr[slot]  = min(hbase[b] + lp[k], NBUCK * CAP - 1);  // OOB-safe
            staged[slot] = pk[k];
        }
    }
    __syncthreads();
    int tot = s_total;
    for (int k = tid; k < tot; k += ABLK)
        tmp[saddr[k]] = staged[k];                        // bucket-contiguous runs
}

// ---------------- scan bucket counts (post-partA) -> cbase for csr compaction ----

__global__ __launch_bounds__(512) void scanC(const int* __restrict__ gcur,
                                             int* __restrict__ cbase,
                                             int* __restrict__ rowptr, int N) {
    __shared__ int wsum[8];
    int t = threadIdx.x, lane = t & 63, wv = t >> 6;
    int v = 0;
    if (t < NBUCK) v = min(gcur[t] - t * CAP, CAP);       // final bucket count
    int s = v;
#pragma unroll
    for (int off = 1; off < 64; off <<= 1) {
        int u = __shfl_up(s, off, 64);
        if (lane >= off) s += u;
    }
    if (lane == 63) wsum[wv] = s;
    __syncthreads();
    int total = 0;
    if (t == 0) { int r = 0; for (int i = 0; i < 8; ++i) { int u = wsum[i]; wsum[i] = r; r += u; } total = r; }
    __syncthreads();
    if (t < NBUCK) cbase[t] = s + wsum[wv] - v;           // exclusive
    if (t == 0) { cbase[NBUCK] = total; rowptr[N] = total; }
}

// ---------------- CSR build, phase B ----------------

__global__ __launch_bounds__(1024) void partB(const int* __restrict__ cbase, const unsigned* __restrict__ tmp,
                      int* __restrict__ rowptr, float* __restrict__ dinv,
                      int* __restrict__ csr_row, int N) {
    __shared__ int hist[BUCK];
    __shared__ int cur[BUCK];
    __shared__ int wsum[4];
    int b = blockIdx.x;
    int node0 = b << BSHIFT;
    int nn = min(BUCK, N - node0);
    int tid = threadIdx.x;
    if (tid < BUCK) hist[tid] = 0;
    __syncthreads();
    int base = cbase[b];
    int cnt  = cbase[b + 1] - base;
    const unsigned* te = tmp + (size_t)b * CAP;
    for (int e = tid; e < cnt; e += 1024)
        atomicAdd(&hist[te[e] >> 17], 1);                 // LDS atomic
    __syncthreads();
    int lane = tid & 63, wv = tid >> 6;
    int d0 = (tid < BUCK) ? hist[tid] : 0;
    int s = d0;
#pragma unroll
    for (int off = 1; off < 64; off <<= 1) {
        int u = __shfl_up(s, off, 64);
        if (lane >= off) s += u;
    }
    if (tid < BUCK && lane == 63) wsum[wv] = s;
    __syncthreads();
    if (tid == 0) { int r = 0; for (int i = 0; i < 4; ++i) { int u = wsum[i]; wsum[i] = r; r += u; } }
    __syncthreads();
    if (tid < BUCK) {
        int excl = s + wsum[wv] - d0;
        cur[tid] = base + excl;
        if (tid < nn) {
            rowptr[node0 + tid] = base + excl;
            dinv[node0 + tid] = rsqrtf((float)(d0 + 1));  // +1 self-loop
        }
    }
    __syncthreads();
    for (int e = tid; e < cnt; e += 1024) {
        unsigned v2 = te[e];
        int lc = (int)(v2 >> 17);
        int pos = atomicAdd(&cur[lc], 1);                 // LDS atomic
        csr_row[pos] = (int)(v2 & 0x1FFFFu);
    }
}

// ---------------- layer 1 GEMM: hs = fp16((x @ W1) * dinv), one 32B record/node --

__global__ void gemm1_kernel(const float* __restrict__ x, const float* __restrict__ W,
                             const float* __restrict__ dinv, __half* __restrict__ hs) {
    __shared__ float Wl[DD * HH];
    __shared__ float xs[16 * DD];
    int tid = threadIdx.x;
    for (int i = tid; i < DD * HH; i += 256) Wl[i] = W[i];
    size_t base = (size_t)blockIdx.x * 16 * DD;
    const float4* xv = (const float4*)(x + base);
    float4* xsv = (float4*)xs;
    xsv[tid]       = xv[tid];
    xsv[tid + 256] = xv[tid + 256];
    __syncthreads();
    int g = tid >> 4, f = tid & 15;
    int n = blockIdx.x * 16 + g;
    float val = 0.f;
    if (f < HH) {
        const float* xrow = xs + g * DD;
        float acc = 0.f;
#pragma unroll 8
        for (int k = 0; k < DD; ++k) acc += xrow[k] * Wl[k * HH + f];
        val = acc * dinv[n];
    }
    hs[(size_t)n * 16 + f] = __float2half(val);
}

// ---------------- gather aggregation (fp16 table, fp32 accumulate) -----------------
// 16 lanes per node (q in [0,2) x eg in [0,8)), 4 nodes per wave.
// FUSE=1: epilogue = fp16(relu(agg+bias) @ W * dinv) -> next hs.
// FUSE=2: epilogue = relu(agg+bias) @ Wc + bc -> out (final layer; gemm_out fused).

__device__ inline void accU(float4& a0, float4& a1, const uint4& u) {
    float2 f0 = __half22float2(*(const __half2*)&u.x);
    float2 f1 = __half22float2(*(const __half2*)&u.y);
    float2 f2 = __half22float2(*(const __half2*)&u.z);
    float2 f3 = __half22float2(*(const __half2*)&u.w);
    a0.x += f0.x; a0.y += f0.y; a0.z += f1.x; a0.w += f1.y;
    a1.x += f2.x; a1.y += f2.y; a1.z += f3.x; a1.w += f3.y;
}

__device__ inline float4 shfl_down4(float4 v, int off) {
    v.x = __shfl_down(v.x, off, 64);
    v.y = __shfl_down(v.y, off, 64);
    v.z = __shfl_down(v.z, off, 64);
    v.w = __shfl_down(v.w, off, 64);
    return v;
}

template <int FUSE>
__global__ __launch_bounds__(256, 5)
void aggregate_kernel(const int* __restrict__ rowptr, const int* __restrict__ csr_row,
                      const float* __restrict__ dinv, const __half* __restrict__ hs,
                      const float* __restrict__ bias, const float* __restrict__ W,
                      const float* __restrict__ bc,
                      __half* __restrict__ hsout, float* __restrict__ outF, int N) {
    __shared__ float Wl[FUSE == 2 ? HH * DD : 256];      // FUSE2: Wc [15][128]
    __shared__ float bs[16];
    __shared__ float bcs[FUSE == 2 ? DD : 1];
    __shared__ float sout[FUSE == 2 ? 16 * DD : 1];      // FUSE2: result transpose
    int tid = threadIdx.x;
    if (FUSE == 1) {
        int k = tid >> 4, f = tid & 15;
        Wl[tid] = (k < HH && f < HH) ? W[k * HH + f] : 0.f;
        if (tid < 16) bs[tid] = (tid < HH) ? bias[tid] : 0.f;
        __syncthreads();
    } else if (FUSE == 2) {
        for (int i = tid; i < HH * DD; i += 256) Wl[i] = W[i];   // row-major [k][f]
        if (tid < 16) bs[tid] = (tid < HH) ? bias[tid] : 0.f;
        if (tid < DD) bcs[tid] = bc[tid];
        __syncthreads();
    }
    int wid = (blockIdx.x * 256 + tid) >> 6;
    int lane = tid & 63;
    int sub = lane & 15;
    int c = wid * 4 + (lane >> 4);
    int q = sub & 1, eg = sub >> 1;            // eg in [0,8)
    int s = 0, epe = 0;
    if (c < N) { s = rowptr[c]; epe = rowptr[c + 1]; }
    const uint4* h8 = (const uint4*)hs;        // 2 uint4 per node record
    float4 a0 = make_float4(0.f, 0.f, 0.f, 0.f), a1 = a0;
    int e = s + eg;
    for (; e + 56 < epe; e += 64) {
        int i0 = csr_row[e];      int i1 = csr_row[e + 8];
        int i2 = csr_row[e + 16]; int i3 = csr_row[e + 24];
        int i4 = csr_row[e + 32]; int i5 = csr_row[e + 40];
        int i6 = csr_row[e + 48]; int i7 = csr_row[e + 56];
        uint4 v0 = h8[((size_t)i0 << 1) + q];
        uint4 v1 = h8[((size_t)i1 << 1) + q];
        uint4 v2 = h8[((size_t)i2 << 1) + q];
        uint4 v3 = h8[((size_t)i3 << 1) + q];
        uint4 v4 = h8[((size_t)i4 << 1) + q];
        uint4 v5 = h8[((size_t)i5 << 1) + q];
        uint4 v6 = h8[((size_t)i6 << 1) + q];
        uint4 v7 = h8[((size_t)i7 << 1) + q];
        accU(a0, a1, v0); accU(a0, a1, v1); accU(a0, a1, v2); accU(a0, a1, v3);
        accU(a0, a1, v4); accU(a0, a1, v5); accU(a0, a1, v6); accU(a0, a1, v7);
    }
    for (; e + 8 < epe; e += 16) {
        int i0 = csr_row[e]; int i1 = csr_row[e + 8];
        uint4 v0 = h8[((size_t)i0 << 1) + q];
        uint4 v1 = h8[((size_t)i1 << 1) + q];
        accU(a0, a1, v0); accU(a0, a1, v1);
    }
    if (e < epe) {
        uint4 v0 = h8[((size_t)csr_row[e] << 1) + q];
        accU(a0, a1, v0);
    }
#define RED4(off) { float4 t0_ = shfl_down4(a0, off); float4 t1_ = shfl_down4(a1, off); \
                    a0.x += t0_.x; a0.y += t0_.y; a0.z += t0_.z; a0.w += t0_.w; \
                    a1.x += t1_.x; a1.y += t1_.y; a1.z += t1_.z; a1.w += t1_.w; }
    RED4(8) RED4(4) RED4(2)
#undef RED4
    float d = (c < N) ? dinv[c] : 0.f;
    float4 o0 = make_float4(0.f, 0.f, 0.f, 0.f), o1 = o0;
    if (sub < 2 && c < N) {
        uint4 su = h8[((size_t)c << 1) + q];   // self record half
        float2 s0 = __half22float2(*(const __half2*)&su.x);
        float2 s1 = __half22float2(*(const __half2*)&su.y);
        float2 s2 = __half22float2(*(const __half2*)&su.z);
        float2 s3 = __half22float2(*(const __half2*)&su.w);
        o0.x = d * (a0.x + s0.x); o0.y = d * (a0.y + s0.y);
        o0.z = d * (a0.z + s1.x); o0.w = d * (a0.w + s1.y);
        o1.x = d * (a1.x + s2.x); o1.y = d * (a1.y + s2.y);
        o1.z = d * (a1.z + s3.x); o1.w = d * (a1.w + s3.y);
        // bias + relu (shared by FUSE 1/2 epilogues)
        int bb = q * 8;
        o0.x = fmaxf(o0.x + bs[bb + 0], 0.f); o0.y = fmaxf(o0.y + bs[bb + 1], 0.f);
        o0.z = fmaxf(o0.z + bs[bb + 2], 0.f); o0.w = fmaxf(o0.w + bs[bb + 3], 0.f);
        o1.x = fmaxf(o1.x + bs[bb + 4], 0.f); o1.y = fmaxf(o1.y + bs[bb + 5], 0.f);
        o1.z = fmaxf(o1.z + bs[bb + 6], 0.f); o1.w = fmaxf(o1.w + bs[bb + 7], 0.f);
    }
    // broadcast the relu'd 16-vector to all 16 lanes of the node group
    int base = lane & ~15;
    float va[8], vb[8];
    va[0] = __shfl(o0.x, base, 64); va[1] = __shfl(o0.y, base, 64);
    va[2] = __shfl(o0.z, base, 64); va[3] = __shfl(o0.w, base, 64);
    va[4] = __shfl(o1.x, base, 64); va[5] = __shfl(o1.y, base, 64);
    va[6] = __shfl(o1.z, base, 64); va[7] = __shfl(o1.w, base, 64);
    vb[0] = __shfl(o0.x, base + 1, 64); vb[1] = __shfl(o0.y, base + 1, 64);
    vb[2] = __shfl(o0.z, base + 1, 64); vb[3] = __shfl(o0.w, base + 1, 64);
    vb[4] = __shfl(o1.x, base + 1, 64); vb[5] = __shfl(o1.y, base + 1, 64);
    vb[6] = __shfl(o1.z, base + 1, 64); vb[7] = __shfl(o1.w, base + 1, 64);
    if (FUSE == 1) {
        float acc = 0.f;
#pragma unroll
        for (int k = 0; k < 8; ++k) acc += va[k] * Wl[k * 16 + sub];
#pragma unroll
        for (int k = 0; k < 8; ++k) acc += vb[k] * Wl[(8 + k) * 16 + sub];
        if (c < N) hsout[(size_t)c * 16 + sub] = __float2half(acc * d);
    } else if (FUSE == 2) {
        // lane sub computes features f = sub + 16j (conflict-free Wl reads),
        // results staged in LDS, then coalesced float4 writes.
        int nl = (tid >> 4);                   // node index within block [0,16)
#pragma unroll
        for (int j = 0; j < 8; ++j) {
            int f = sub + 16 * j;
            float acc = bcs[f];
#pragma unroll
            for (int k = 0; k < 8; ++k)  acc += va[k] * Wl[k * DD + f];
#pragma unroll
            for (int k = 0; k < 7; ++k)  acc += vb[k] * Wl[(8 + k) * DD + f];
            sout[nl * DD + f] = acc;
        }
        __syncthreads();
        int n0 = blockIdx.x * 16;
        const float4* sv = (const float4*)sout;
#pragma unroll
        for (int r = 0; r < 2; ++r) {
            int idx = tid + 256 * r;           // 512 float4 = 16 nodes x 128 f
            int node = idx >> 5, rem = idx & 31;
            if (n0 + node < N)
                ((float4*)outF)[((size_t)(n0 + node) * DD >> 2) + rem] = sv[idx];
        }
    }
}

// ---------------- launch ----------------

extern "C" void kernel_launch(void* const* d_in, const int* in_sizes, int n_in,
                              void* d_out, int out_size, void* d_ws, size_t ws_size,
                              hipStream_t stream) {
    const float* x  = (const float*)d_in[0];
    const int*   ei = (const int*)d_in[1];
    const float* W1 = (const float*)d_in[2];
    const float* b1 = (const float*)d_in[3];
    const float* W2 = (const float*)d_in[4];
    const float* b2 = (const float*)d_in[5];
    const float* W3 = (const float*)d_in[6];
    const float* b3 = (const float*)d_in[7];
    const float* Wc = (const float*)d_in[8];
    const float* bc = (const float*)d_in[9];
    float* out = (float*)d_out;

    int N = in_sizes[0] / DD;   // 100000
    int E = in_sizes[1] / 2;    // 6400000
    const int* row = ei;        // edge_index[0] = source
    const int* col = ei + E;    // edge_index[1] = target

    char* ws = (char*)d_ws;
    size_t off = 0;
    auto alloc = [&](size_t bytes) {
        void* p = ws + off;
        off += (bytes + 255) & ~(size_t)255;
        return p;
    };
    float*    dinv    = (float*)   alloc((size_t)N * 4);
    int*      rowptr  = (int*)     alloc((size_t)(N + 1) * 4);
    int*      gcur    = (int*)     alloc((size_t)NBUCK * 4);
    int*      cbase   = (int*)     alloc((size_t)(NBUCK + 1) * 4);
    int*      csr_row = (int*)     alloc((size_t)E * 4 + 256);           // 25.6 MB (+pad)
    unsigned* tmp     = (unsigned*)alloc((size_t)NBUCK * CAP * 4);       // 28.8 MB
    (void)n_in; (void)out_size; (void)ws_size;

    // hsA/hsB (N x 16 halves = 3.2 MB each) alias tmp — tmp dead after partB.
    __half* hsA = (__half*)tmp;
    __half* hsB = (__half*)((char*)tmp + (size_t)N * 32);

    int eblocks = (E + CHUNK - 1) / CHUNK;             // 6143 = 3 x 2048 pipes

    // CSR build: no counting pre-pass — fixed-capacity bucket regions.
    init_gcur<<<1, 512, 0, stream>>>(gcur);
    partA<<<eblocks, ABLK, 0, stream>>>(row, col, gcur, tmp, E);
    scanC<<<1, 512, 0, stream>>>(gcur, cbase, rowptr, N);
    partB<<<NBUCK, 1024, 0, stream>>>(cbase, tmp, rowptr, dinv, csr_row, N);

    int nb16 = (N + 15) / 16;                          // 6250
    int aggblocks = (N + 15) / 16;                     // 4 nodes/wave x 4 waves/block

    // layer 1 GEMM
    gemm1_kernel<<<nb16, 256, 0, stream>>>(x, W1, dinv, hsA);
    // aggregate 1 + fused layer-2 GEMM
    aggregate_kernel<1><<<aggblocks, 256, 0, stream>>>(rowptr, csr_row, dinv, hsA,
                                                       b1, W2, nullptr, hsB, nullptr, N);
    // aggregate 2 + fused layer-3 GEMM
    aggregate_kernel<1><<<aggblocks, 256, 0, stream>>>(rowptr, csr_row, dinv, hsB,
                                                       b2, W3, nullptr, hsA, nullptr, N);
    // aggregate 3 + fused output GEMM (writes out directly)
    aggregate_kernel<2><<<aggblocks, 256, 0, stream>>>(rowptr, csr_row, dinv, hsA,
                                                       b3, Wc, bc, nullptr, out, N);
}

// Round 8
// 395.795 us; speedup vs baseline: 1.4831x; 1.4831x over previous
//
#include <hip/hip_runtime.h>
#include <hip/hip_fp16.h>

#define DD 128
#define HH 15
#define BSHIFT 8                 // 256 nodes per bucket
#define BUCK (1 << BSHIFT)
#define NBUCK 391                // ceil(100000 / 256)
#define CAP 18432                // fixed bucket capacity: mean 16368 + 16 sigma
#define CHUNK 4096               // edges per partA block (run length ~10.5/bucket)
#define ABLK 512                 // partA block size

// ---------------- init: absolute bucket cursors at fixed capacity ----------------

__global__ __launch_bounds__(512) void init_gcur(int* __restrict__ gcur) {
    int i = threadIdx.x;
    if (i < NBUCK) gcur[i] = i * CAP;
}

// ---------------- CSR build, phase A: LDS-staged bucket binning ----------------
// pack = row (17b) | local_col (8b) << 17. Fixed-capacity bucket regions in tmp.
// NOTE (R7 lesson): per-block cost scales with nblocks*NBUCK (gcur atomics,
// histo/scan, partial-line scatter runs). Keep CHUNK large; 1563 blocks.

__global__ __launch_bounds__(512) void partA(const int* __restrict__ row, const int* __restrict__ col,
                      int* __restrict__ gcur, unsigned* __restrict__ tmp, int E) {
    __shared__ int histo[NBUCK];
    __shared__ int hbase[NBUCK];
    __shared__ int hscan[NBUCK];
    __shared__ int wsum[8];
    __shared__ int s_total;
    __shared__ unsigned staged[CHUNK];
    __shared__ int saddr[CHUNK];
    int tid = threadIdx.x;
    int start = blockIdx.x * CHUNK;
    for (int i = tid; i < NBUCK; i += ABLK) histo[i] = 0;
    __syncthreads();
    unsigned pk[8]; unsigned short lp[8]; unsigned short bk[8];
    for (int k = 0; k < 8; ++k) {
        int e = start + k * ABLK + tid;
        bk[k] = 0xFFFF;
        if (e < E) {
            int cc = col[e];
            int b = cc >> BSHIFT;
            int rr = row[e];
            pk[k] = (unsigned)rr | ((unsigned)(cc & (BUCK - 1)) << 17);
            bk[k] = (unsigned short)b;
            lp[k] = (unsigned short)atomicAdd(&histo[b], 1);
        }
    }
    __syncthreads();
    int lane = tid & 63, wv = tid >> 6;
    int v = (tid < NBUCK) ? histo[tid] : 0;
    int s = v;
#pragma unroll
    for (int off = 1; off < 64; off <<= 1) {
        int u = __shfl_up(s, off, 64);
        if (lane >= off) s += u;
    }
    if (lane == 63) wsum[wv] = s;
    __syncthreads();
    if (tid == 0) {
        int r = 0;
        for (int i = 0; i < 8; ++i) { int u = wsum[i]; wsum[i] = r; r += u; }
        s_total = r;
    }
    __syncthreads();
    if (tid < NBUCK) {
        int excl = s + wsum[wv] - v;                      // chunk-local exclusive
        hscan[tid] = excl;
        if (v > 0) hbase[tid] = atomicAdd(&gcur[tid], v); // reserve absolute run
    }
    __syncthreads();
    for (int k = 0; k < 8; ++k) {
        if (bk[k] != 0xFFFF) {
            int b = bk[k];
            int slot = hscan[b] + lp[k];
            saddr[slot]  = min(hbase[b] + lp[k], NBUCK * CAP - 1);  // OOB-safe
            staged[slot] = pk[k];
        }
    }
    __syncthreads();
    int tot = s_total;
    for (int k = tid; k < tot; k += ABLK)
        tmp[saddr[k]] = staged[k];                        // bucket-contiguous runs
}

// ---------------- scan bucket counts (post-partA) -> cbase for csr compaction ----

__global__ __launch_bounds__(512) void scanC(const int* __restrict__ gcur,
                                             int* __restrict__ cbase,
                                             int* __restrict__ rowptr, int N) {
    __shared__ int wsum[8];
    int t = threadIdx.x, lane = t & 63, wv = t >> 6;
    int v = 0;
    if (t < NBUCK) v = min(gcur[t] - t * CAP, CAP);       // final bucket count
    int s = v;
#pragma unroll
    for (int off = 1; off < 64; off <<= 1) {
        int u = __shfl_up(s, off, 64);
        if (lane >= off) s += u;
    }
    if (lane == 63) wsum[wv] = s;
    __syncthreads();
    int total = 0;
    if (t == 0) { int r = 0; for (int i = 0; i < 8; ++i) { int u = wsum[i]; wsum[i] = r; r += u; } total = r; }
    __syncthreads();
    if (t < NBUCK) cbase[t] = s + wsum[wv] - v;           // exclusive
    if (t == 0) { cbase[NBUCK] = total; rowptr[N] = total; }
}

// ---------------- CSR build, phase B ----------------

__global__ __launch_bounds__(1024) void partB(const int* __restrict__ cbase, const unsigned* __restrict__ tmp,
                      int* __restrict__ rowptr, float* __restrict__ dinv,
                      int* __restrict__ csr_row, int N) {
    __shared__ int hist[BUCK];
    __shared__ int cur[BUCK];
    __shared__ int wsum[4];
    int b = blockIdx.x;
    int node0 = b << BSHIFT;
    int nn = min(BUCK, N - node0);
    int tid = threadIdx.x;
    if (tid < BUCK) hist[tid] = 0;
    __syncthreads();
    int base = cbase[b];
    int cnt  = cbase[b + 1] - base;
    const unsigned* te = tmp + (size_t)b * CAP;
    for (int e = tid; e < cnt; e += 1024)
        atomicAdd(&hist[te[e] >> 17], 1);                 // LDS atomic
    __syncthreads();
    int lane = tid & 63, wv = tid >> 6;
    int d0 = (tid < BUCK) ? hist[tid] : 0;
    int s = d0;
#pragma unroll
    for (int off = 1; off < 64; off <<= 1) {
        int u = __shfl_up(s, off, 64);
        if (lane >= off) s += u;
    }
    if (tid < BUCK && lane == 63) wsum[wv] = s;
    __syncthreads();
    if (tid == 0) { int r = 0; for (int i = 0; i < 4; ++i) { int u = wsum[i]; wsum[i] = r; r += u; } }
    __syncthreads();
    if (tid < BUCK) {
        int excl = s + wsum[wv] - d0;
        cur[tid] = base + excl;
        if (tid < nn) {
            rowptr[node0 + tid] = base + excl;
            dinv[node0 + tid] = rsqrtf((float)(d0 + 1));  // +1 self-loop
        }
    }
    __syncthreads();
    for (int e = tid; e < cnt; e += 1024) {
        unsigned v2 = te[e];
        int lc = (int)(v2 >> 17);
        int pos = atomicAdd(&cur[lc], 1);                 // LDS atomic
        csr_row[pos] = (int)(v2 & 0x1FFFFu);
    }
}

// ---------------- layer 1 GEMM: hs = fp16((x @ W1) * dinv), one 32B record/node --

__global__ void gemm1_kernel(const float* __restrict__ x, const float* __restrict__ W,
                             const float* __restrict__ dinv, __half* __restrict__ hs) {
    __shared__ float Wl[DD * HH];
    __shared__ float xs[16 * DD];
    int tid = threadIdx.x;
    for (int i = tid; i < DD * HH; i += 256) Wl[i] = W[i];
    size_t base = (size_t)blockIdx.x * 16 * DD;
    const float4* xv = (const float4*)(x + base);
    float4* xsv = (float4*)xs;
    xsv[tid]       = xv[tid];
    xsv[tid + 256] = xv[tid + 256];
    __syncthreads();
    int g = tid >> 4, f = tid & 15;
    int n = blockIdx.x * 16 + g;
    float val = 0.f;
    if (f < HH) {
        const float* xrow = xs + g * DD;
        float acc = 0.f;
#pragma unroll 8
        for (int k = 0; k < DD; ++k) acc += xrow[k] * Wl[k * HH + f];
        val = acc * dinv[n];
    }
    hs[(size_t)n * 16 + f] = __float2half(val);
}

// ---------------- gather aggregation (fp16 table, fp32 accumulate) -----------------
// 16 lanes per node (q in [0,2) x eg in [0,8)), 4 nodes per wave.
// FUSE=1: epilogue = fp16(relu(agg+bias) @ W * dinv) -> next hs.
// FUSE=2: epilogue = relu(agg+bias) @ Wc + bc -> out (final layer; gemm_out fused).

__device__ inline void accU(float4& a0, float4& a1, const uint4& u) {
    float2 f0 = __half22float2(*(const __half2*)&u.x);
    float2 f1 = __half22float2(*(const __half2*)&u.y);
    float2 f2 = __half22float2(*(const __half2*)&u.z);
    float2 f3 = __half22float2(*(const __half2*)&u.w);
    a0.x += f0.x; a0.y += f0.y; a0.z += f1.x; a0.w += f1.y;
    a1.x += f2.x; a1.y += f2.y; a1.z += f3.x; a1.w += f3.y;
}

__device__ inline float4 shfl_down4(float4 v, int off) {
    v.x = __shfl_down(v.x, off, 64);
    v.y = __shfl_down(v.y, off, 64);
    v.z = __shfl_down(v.z, off, 64);
    v.w = __shfl_down(v.w, off, 64);
    return v;
}

template <int FUSE>
__global__ __launch_bounds__(256, 2)
void aggregate_kernel(const int* __restrict__ rowptr, const int* __restrict__ csr_row,
                      const float* __restrict__ dinv, const __half* __restrict__ hs,
                      const float* __restrict__ bias, const float* __restrict__ W,
                      const float* __restrict__ bc,
                      __half* __restrict__ hsout, float* __restrict__ outF, int N) {
    __shared__ float Wl[FUSE == 2 ? HH * DD : 256];      // FUSE2: Wc [15][128]
    __shared__ float bs[16];
    __shared__ float bcs[FUSE == 2 ? DD : 1];
    __shared__ float sout[FUSE == 2 ? 16 * DD : 1];      // FUSE2: result transpose
    int tid = threadIdx.x;
    if (FUSE == 1) {
        int k = tid >> 4, f = tid & 15;
        Wl[tid] = (k < HH && f < HH) ? W[k * HH + f] : 0.f;
        if (tid < 16) bs[tid] = (tid < HH) ? bias[tid] : 0.f;
        __syncthreads();
    } else if (FUSE == 2) {
        for (int i = tid; i < HH * DD; i += 256) Wl[i] = W[i];   // row-major [k][f]
        if (tid < 16) bs[tid] = (tid < HH) ? bias[tid] : 0.f;
        if (tid < DD) bcs[tid] = bc[tid];
        __syncthreads();
    }
    int wid = (blockIdx.x * 256 + tid) >> 6;
    int lane = tid & 63;
    int sub = lane & 15;
    int c = wid * 4 + (lane >> 4);
    int q = sub & 1, eg = sub >> 1;            // eg in [0,8)
    int s = 0, epe = 0;
    if (c < N) { s = rowptr[c]; epe = rowptr[c + 1]; }
    const uint4* h8 = (const uint4*)hs;        // 2 uint4 per node record
    float4 a0 = make_float4(0.f, 0.f, 0.f, 0.f), a1 = a0;
    int e = s + eg;
    for (; e + 56 < epe; e += 64) {
        int i0 = csr_row[e];      int i1 = csr_row[e + 8];
        int i2 = csr_row[e + 16]; int i3 = csr_row[e + 24];
        int i4 = csr_row[e + 32]; int i5 = csr_row[e + 40];
        int i6 = csr_row[e + 48]; int i7 = csr_row[e + 56];
        uint4 v0 = h8[((size_t)i0 << 1) + q];
        uint4 v1 = h8[((size_t)i1 << 1) + q];
        uint4 v2 = h8[((size_t)i2 << 1) + q];
        uint4 v3 = h8[((size_t)i3 << 1) + q];
        uint4 v4 = h8[((size_t)i4 << 1) + q];
        uint4 v5 = h8[((size_t)i5 << 1) + q];
        uint4 v6 = h8[((size_t)i6 << 1) + q];
        uint4 v7 = h8[((size_t)i7 << 1) + q];
        accU(a0, a1, v0); accU(a0, a1, v1); accU(a0, a1, v2); accU(a0, a1, v3);
        accU(a0, a1, v4); accU(a0, a1, v5); accU(a0, a1, v6); accU(a0, a1, v7);
    }
    for (; e + 8 < epe; e += 16) {
        int i0 = csr_row[e]; int i1 = csr_row[e + 8];
        uint4 v0 = h8[((size_t)i0 << 1) + q];
        uint4 v1 = h8[((size_t)i1 << 1) + q];
        accU(a0, a1, v0); accU(a0, a1, v1);
    }
    if (e < epe) {
        uint4 v0 = h8[((size_t)csr_row[e] << 1) + q];
        accU(a0, a1, v0);
    }
#define RED4(off) { float4 t0_ = shfl_down4(a0, off); float4 t1_ = shfl_down4(a1, off); \
                    a0.x += t0_.x; a0.y += t0_.y; a0.z += t0_.z; a0.w += t0_.w; \
                    a1.x += t1_.x; a1.y += t1_.y; a1.z += t1_.z; a1.w += t1_.w; }
    RED4(8) RED4(4) RED4(2)
#undef RED4
    float d = (c < N) ? dinv[c] : 0.f;
    float4 o0 = make_float4(0.f, 0.f, 0.f, 0.f), o1 = o0;
    if (sub < 2 && c < N) {
        uint4 su = h8[((size_t)c << 1) + q];   // self record half
        float2 s0 = __half22float2(*(const __half2*)&su.x);
        float2 s1 = __half22float2(*(const __half2*)&su.y);
        float2 s2 = __half22float2(*(const __half2*)&su.z);
        float2 s3 = __half22float2(*(const __half2*)&su.w);
        o0.x = d * (a0.x + s0.x); o0.y = d * (a0.y + s0.y);
        o0.z = d * (a0.z + s1.x); o0.w = d * (a0.w + s1.y);
        o1.x = d * (a1.x + s2.x); o1.y = d * (a1.y + s2.y);
        o1.z = d * (a1.z + s3.x); o1.w = d * (a1.w + s3.y);
        // bias + relu (shared by FUSE 1/2 epilogues)
        int bb = q * 8;
        o0.x = fmaxf(o0.x + bs[bb + 0], 0.f); o0.y = fmaxf(o0.y + bs[bb + 1], 0.f);
        o0.z = fmaxf(o0.z + bs[bb + 2], 0.f); o0.w = fmaxf(o0.w + bs[bb + 3], 0.f);
        o1.x = fmaxf(o1.x + bs[bb + 4], 0.f); o1.y = fmaxf(o1.y + bs[bb + 5], 0.f);
        o1.z = fmaxf(o1.z + bs[bb + 6], 0.f); o1.w = fmaxf(o1.w + bs[bb + 7], 0.f);
    }
    // broadcast the relu'd 16-vector to all 16 lanes of the node group
    int base = lane & ~15;
    float va[8], vb[8];
    va[0] = __shfl(o0.x, base, 64); va[1] = __shfl(o0.y, base, 64);
    va[2] = __shfl(o0.z, base, 64); va[3] = __shfl(o0.w, base, 64);
    va[4] = __shfl(o1.x, base, 64); va[5] = __shfl(o1.y, base, 64);
    va[6] = __shfl(o1.z, base, 64); va[7] = __shfl(o1.w, base, 64);
    vb[0] = __shfl(o0.x, base + 1, 64); vb[1] = __shfl(o0.y, base + 1, 64);
    vb[2] = __shfl(o0.z, base + 1, 64); vb[3] = __shfl(o0.w, base + 1, 64);
    vb[4] = __shfl(o1.x, base + 1, 64); vb[5] = __shfl(o1.y, base + 1, 64);
    vb[6] = __shfl(o1.z, base + 1, 64); vb[7] = __shfl(o1.w, base + 1, 64);
    if (FUSE == 1) {
        float acc = 0.f;
#pragma unroll
        for (int k = 0; k < 8; ++k) acc += va[k] * Wl[k * 16 + sub];
#pragma unroll
        for (int k = 0; k < 8; ++k) acc += vb[k] * Wl[(8 + k) * 16 + sub];
        if (c < N) hsout[(size_t)c * 16 + sub] = __float2half(acc * d);
    } else if (FUSE == 2) {
        // lane sub computes features f = sub + 16j (conflict-free Wl reads),
        // results staged in LDS, then coalesced float4 writes.
        int nl = (tid >> 4);                   // node index within block [0,16)
#pragma unroll
        for (int j = 0; j < 8; ++j) {
            int f = sub + 16 * j;
            float acc = bcs[f];
#pragma unroll
            for (int k = 0; k < 8; ++k)  acc += va[k] * Wl[k * DD + f];
#pragma unroll
            for (int k = 0; k < 7; ++k)  acc += vb[k] * Wl[(8 + k) * DD + f];
            sout[nl * DD + f] = acc;
        }
        __syncthreads();
        int n0 = blockIdx.x * 16;
        const float4* sv = (const float4*)sout;
#pragma unroll
        for (int r = 0; r < 2; ++r) {
            int idx = tid + 256 * r;           // 512 float4 = 16 nodes x 128 f
            int node = idx >> 5, rem = idx & 31;
            if (n0 + node < N)
                ((float4*)outF)[((size_t)(n0 + node) * DD >> 2) + rem] = sv[idx];
        }
    }
}

// ---------------- launch ----------------

extern "C" void kernel_launch(void* const* d_in, const int* in_sizes, int n_in,
                              void* d_out, int out_size, void* d_ws, size_t ws_size,
                              hipStream_t stream) {
    const float* x  = (const float*)d_in[0];
    const int*   ei = (const int*)d_in[1];
    const float* W1 = (const float*)d_in[2];
    const float* b1 = (const float*)d_in[3];
    const float* W2 = (const float*)d_in[4];
    const float* b2 = (const float*)d_in[5];
    const float* W3 = (const float*)d_in[6];
    const float* b3 = (const float*)d_in[7];
    const float* Wc = (const float*)d_in[8];
    const float* bc = (const float*)d_in[9];
    float* out = (float*)d_out;

    int N = in_sizes[0] / DD;   // 100000
    int E = in_sizes[1] / 2;    // 6400000
    const int* row = ei;        // edge_index[0] = source
    const int* col = ei + E;    // edge_index[1] = target

    char* ws = (char*)d_ws;
    size_t off = 0;
    auto alloc = [&](size_t bytes) {
        void* p = ws + off;
        off += (bytes + 255) & ~(size_t)255;
        return p;
    };
    float*    dinv    = (float*)   alloc((size_t)N * 4);
    int*      rowptr  = (int*)     alloc((size_t)(N + 1) * 4);
    int*      gcur    = (int*)     alloc((size_t)NBUCK * 4);
    int*      cbase   = (int*)     alloc((size_t)(NBUCK + 1) * 4);
    int*      csr_row = (int*)     alloc((size_t)E * 4 + 256);           // 25.6 MB (+pad)
    unsigned* tmp     = (unsigned*)alloc((size_t)NBUCK * CAP * 4);       // 28.8 MB
    (void)n_in; (void)out_size; (void)ws_size;

    // hsA/hsB (N x 16 halves = 3.2 MB each) alias tmp — tmp dead after partB.
    __half* hsA = (__half*)tmp;
    __half* hsB = (__half*)((char*)tmp + (size_t)N * 32);

    int eblocks = (E + CHUNK - 1) / CHUNK;             // 1563

    // CSR build: no counting pre-pass — fixed-capacity bucket regions.
    init_gcur<<<1, 512, 0, stream>>>(gcur);
    partA<<<eblocks, ABLK, 0, stream>>>(row, col, gcur, tmp, E);
    scanC<<<1, 512, 0, stream>>>(gcur, cbase, rowptr, N);
    partB<<<NBUCK, 1024, 0, stream>>>(cbase, tmp, rowptr, dinv, csr_row, N);

    int nb16 = (N + 15) / 16;                          // 6250
    int aggblocks = (N + 15) / 16;                     // 4 nodes/wave x 4 waves/block

    // layer 1 GEMM
    gemm1_kernel<<<nb16, 256, 0, stream>>>(x, W1, dinv, hsA);
    // aggregate 1 + fused layer-2 GEMM
    aggregate_kernel<1><<<aggblocks, 256, 0, stream>>>(rowptr, csr_row, dinv, hsA,
                                                       b1, W2, nullptr, hsB, nullptr, N);
    // aggregate 2 + fused layer-3 GEMM
    aggregate_kernel<1><<<aggblocks, 256, 0, stream>>>(rowptr, csr_row, dinv, hsB,
                                                       b2, W3, nullptr, hsA, nullptr, N);
    // aggregate 3 + fused output GEMM (writes out directly)
    aggregate_kernel<2><<<aggblocks, 256, 0, stream>>>(rowptr, csr_row, dinv, hsA,
                                                       b3, Wc, bc, nullptr, out, N);
}

// Round 9
// 388.501 us; speedup vs baseline: 1.5109x; 1.0188x over previous
//
#include <hip/hip_runtime.h>
#include <hip/hip_fp16.h>

#define DD 128
#define HH 15
#define BSHIFT 8                 // 256 nodes per bucket
#define BUCK (1 << BSHIFT)
#define NBUCK 391                // ceil(100000 / 256)
#define CAP 18432                // fixed bucket capacity: mean 16368 + 16 sigma
#define CHUNK 4096               // edges per partA block (run length ~10.5/bucket)
#define ABLK 512                 // partA block size
#define XSTR 132                 // padded LDS x-row stride (floats): breaks 128-stride bank conflict

// ---------------- init: absolute bucket cursors at fixed capacity ----------------

__global__ __launch_bounds__(512) void init_gcur(int* __restrict__ gcur) {
    int i = threadIdx.x;
    if (i < NBUCK) gcur[i] = i * CAP;
}

// ---------------- CSR build, phase A: LDS-staged bucket binning ----------------
// pack = row (17b) | local_col (8b) << 17. Fixed-capacity bucket regions in tmp.
// R7 lesson: per-block cost scales with nblocks*NBUCK — keep CHUNK large (1563 blocks).

__global__ __launch_bounds__(512) void partA(const int* __restrict__ row, const int* __restrict__ col,
                      int* __restrict__ gcur, unsigned* __restrict__ tmp, int E) {
    __shared__ int histo[NBUCK];
    __shared__ int hbase[NBUCK];
    __shared__ int hscan[NBUCK];
    __shared__ int wsum[8];
    __shared__ int s_total;
    __shared__ unsigned staged[CHUNK];
    __shared__ int saddr[CHUNK];
    int tid = threadIdx.x;
    int start = blockIdx.x * CHUNK;
    for (int i = tid; i < NBUCK; i += ABLK) histo[i] = 0;
    __syncthreads();
    unsigned pk[8]; unsigned short lp[8]; unsigned short bk[8];
    for (int k = 0; k < 8; ++k) {
        int e = start + k * ABLK + tid;
        bk[k] = 0xFFFF;
        if (e < E) {
            int cc = col[e];
            int b = cc >> BSHIFT;
            int rr = row[e];
            pk[k] = (unsigned)rr | ((unsigned)(cc & (BUCK - 1)) << 17);
            bk[k] = (unsigned short)b;
            lp[k] = (unsigned short)atomicAdd(&histo[b], 1);
        }
    }
    __syncthreads();
    int lane = tid & 63, wv = tid >> 6;
    int v = (tid < NBUCK) ? histo[tid] : 0;
    int s = v;
#pragma unroll
    for (int off = 1; off < 64; off <<= 1) {
        int u = __shfl_up(s, off, 64);
        if (lane >= off) s += u;
    }
    if (lane == 63) wsum[wv] = s;
    __syncthreads();
    if (tid == 0) {
        int r = 0;
        for (int i = 0; i < 8; ++i) { int u = wsum[i]; wsum[i] = r; r += u; }
        s_total = r;
    }
    __syncthreads();
    if (tid < NBUCK) {
        int excl = s + wsum[wv] - v;                      // chunk-local exclusive
        hscan[tid] = excl;
        if (v > 0) hbase[tid] = atomicAdd(&gcur[tid], v); // reserve absolute run
    }
    __syncthreads();
    for (int k = 0; k < 8; ++k) {
        if (bk[k] != 0xFFFF) {
            int b = bk[k];
            int slot = hscan[b] + lp[k];
            saddr[slot]  = min(hbase[b] + lp[k], NBUCK * CAP - 1);  // OOB-safe
            staged[slot] = pk[k];
        }
    }
    __syncthreads();
    int tot = s_total;
    for (int k = tid; k < tot; k += ABLK)
        tmp[saddr[k]] = staged[k];                        // bucket-contiguous runs
}

// ---------------- CSR build, phase B (+ optional fused layer-1 GEMM) ----------------
// Fixed-capacity csr layout: base = b*CAP (no compaction, no scanC). Emits
// rowstart/rowend/dinv. FG=1: epilogue computes hs = fp16((x @ W1) * dinv)
// for this bucket's 256 nodes (x rows staged in LDS, 4 passes of 64 nodes).

template <int FG>
__global__ __launch_bounds__(1024) void partB(const int* __restrict__ gcur, const unsigned* __restrict__ tmp,
                      int* __restrict__ rowstart, int* __restrict__ rowend,
                      float* __restrict__ dinv, int* __restrict__ csr_row,
                      const float* __restrict__ x, const float* __restrict__ W1,
                      __half* __restrict__ hs, int N) {
    __shared__ int hist[BUCK];
    __shared__ int cur[BUCK];
    __shared__ int wsum[4];
    __shared__ float sdv[BUCK];
    __shared__ float Wl[FG ? DD * HH : 1];
    __shared__ float xs[FG ? 64 * XSTR : 1];
    int b = blockIdx.x;
    int node0 = b << BSHIFT;
    int nn = min(BUCK, N - node0);
    int tid = threadIdx.x;
    if (tid < BUCK) hist[tid] = 0;
    if (FG) for (int i = tid; i < DD * HH; i += 1024) Wl[i] = W1[i];
    __syncthreads();
    int base = b * CAP;
    int cnt  = min(gcur[b] - base, CAP);
    const unsigned* te = tmp + (size_t)base;
    for (int e = tid; e < cnt; e += 1024)
        atomicAdd(&hist[te[e] >> 17], 1);                 // LDS atomic
    __syncthreads();
    int lane = tid & 63, wv = tid >> 6;
    int d0 = (tid < BUCK) ? hist[tid] : 0;
    int s = d0;
#pragma unroll
    for (int off = 1; off < 64; off <<= 1) {
        int u = __shfl_up(s, off, 64);
        if (lane >= off) s += u;
    }
    if (tid < BUCK && lane == 63) wsum[wv] = s;
    __syncthreads();
    if (tid == 0) { int r = 0; for (int i = 0; i < 4; ++i) { int u = wsum[i]; wsum[i] = r; r += u; } }
    __syncthreads();
    if (tid < BUCK) {
        int excl = s + wsum[wv] - d0;
        cur[tid] = base + excl;
        if (tid < nn) {
            rowstart[node0 + tid] = base + excl;
            rowend[node0 + tid]   = base + excl + d0;
            float dv = rsqrtf((float)(d0 + 1));           // +1 self-loop
            dinv[node0 + tid] = dv;
            sdv[tid] = dv;
        }
    }
    __syncthreads();
    for (int e = tid; e < cnt; e += 1024) {
        unsigned v2 = te[e];
        int lc = (int)(v2 >> 17);
        int pos = atomicAdd(&cur[lc], 1);                 // LDS atomic
        csr_row[pos] = (int)(v2 & 0x1FFFFu);
    }
    if (FG) {
        // fused layer-1 GEMM for nodes [node0, node0+256)
        for (int p = 0; p < 4; ++p) {
            __syncthreads();
            for (int j = tid; j < 64 * 32; j += 1024) {   // stage 64 x-rows (f4)
                int r = j >> 5, cidx = j & 31;
                int n = node0 + p * 64 + r;
                float4 vx = make_float4(0.f, 0.f, 0.f, 0.f);
                if (n < N) vx = ((const float4*)x)[(size_t)n * 32 + cidx];
                ((float4*)(xs + r * XSTR))[cidx] = vx;
            }
            __syncthreads();
            int r = tid >> 4, f = tid & 15;
            int n = node0 + p * 64 + r;
            float acc = 0.f;
            if (f < HH) {
                const float* xr = xs + r * XSTR;
#pragma unroll 8
                for (int k = 0; k < DD; ++k) acc += xr[k] * Wl[k * HH + f];
                acc *= sdv[p * 64 + r];
            }
            if (n < N) hs[(size_t)n * 16 + f] = __float2half(acc);
        }
    }
}

// ---------------- standalone layer-1 GEMM (fallback when ws is tight) -----------

__global__ void gemm1_kernel(const float* __restrict__ x, const float* __restrict__ W,
                             const float* __restrict__ dinv, __half* __restrict__ hs) {
    __shared__ float Wl[DD * HH];
    __shared__ float xsl[16 * DD];
    int tid = threadIdx.x;
    for (int i = tid; i < DD * HH; i += 256) Wl[i] = W[i];
    size_t base = (size_t)blockIdx.x * 16 * DD;
    const float4* xv = (const float4*)(x + base);
    float4* xsv = (float4*)xsl;
    xsv[tid]       = xv[tid];
    xsv[tid + 256] = xv[tid + 256];
    __syncthreads();
    int g = tid >> 4, f = tid & 15;
    int n = blockIdx.x * 16 + g;
    float val = 0.f;
    if (f < HH) {
        const float* xrow = xsl + g * DD;
        float acc = 0.f;
#pragma unroll 8
        for (int k = 0; k < DD; ++k) acc += xrow[k] * Wl[k * HH + f];
        val = acc * dinv[n];
    }
    hs[(size_t)n * 16 + f] = __float2half(val);
}

// ---------------- gather aggregation (fp16 table, fp32 accumulate) -----------------
// 16 lanes per node (q in [0,2) x eg in [0,8)), 4 nodes per wave.
// Index-PREFETCH pipeline: iteration k issues iteration k+1's 8 csr indices
// BEFORE k's gathers -> idx->gather chain overlaps across iterations (one L2
// latency per 64 edges instead of two).
// FUSE=1: epilogue = fp16(relu(agg+bias) @ W * dinv) -> next hs.
// FUSE=2: epilogue = relu(agg+bias) @ Wc + bc -> out.

__device__ inline void accU(float4& a0, float4& a1, const uint4& u) {
    float2 f0 = __half22float2(*(const __half2*)&u.x);
    float2 f1 = __half22float2(*(const __half2*)&u.y);
    float2 f2 = __half22float2(*(const __half2*)&u.z);
    float2 f3 = __half22float2(*(const __half2*)&u.w);
    a0.x += f0.x; a0.y += f0.y; a0.z += f1.x; a0.w += f1.y;
    a1.x += f2.x; a1.y += f2.y; a1.z += f3.x; a1.w += f3.y;
}

__device__ inline float4 shfl_down4(float4 v, int off) {
    v.x = __shfl_down(v.x, off, 64);
    v.y = __shfl_down(v.y, off, 64);
    v.z = __shfl_down(v.z, off, 64);
    v.w = __shfl_down(v.w, off, 64);
    return v;
}

template <int FUSE>
__global__ __launch_bounds__(256, 2)
void aggregate_kernel(const int* __restrict__ rowstart, const int* __restrict__ rowend,
                      const int* __restrict__ csr_row,
                      const float* __restrict__ dinv, const __half* __restrict__ hs,
                      const float* __restrict__ bias, const float* __restrict__ W,
                      const float* __restrict__ bc,
                      __half* __restrict__ hsout, float* __restrict__ outF, int N) {
    __shared__ float Wl[FUSE == 2 ? HH * DD : 256];      // FUSE2: Wc [15][128]
    __shared__ float bs[16];
    __shared__ float bcs[FUSE == 2 ? DD : 1];
    __shared__ float sout[FUSE == 2 ? 16 * DD : 1];      // FUSE2: result transpose
    int tid = threadIdx.x;
    if (FUSE == 1) {
        int k = tid >> 4, f = tid & 15;
        Wl[tid] = (k < HH && f < HH) ? W[k * HH + f] : 0.f;
        if (tid < 16) bs[tid] = (tid < HH) ? bias[tid] : 0.f;
        __syncthreads();
    } else if (FUSE == 2) {
        for (int i = tid; i < HH * DD; i += 256) Wl[i] = W[i];   // row-major [k][f]
        if (tid < 16) bs[tid] = (tid < HH) ? bias[tid] : 0.f;
        if (tid < DD) bcs[tid] = bc[tid];
        __syncthreads();
    }
    int wid = (blockIdx.x * 256 + tid) >> 6;
    int lane = tid & 63;
    int sub = lane & 15;
    int c = wid * 4 + (lane >> 4);
    int q = sub & 1, eg = sub >> 1;            // eg in [0,8)
    int s = 0, epe = 0;
    if (c < N) { s = rowstart[c]; epe = rowend[c]; }
    const uint4* h8 = (const uint4*)hs;        // 2 uint4 per node record
    float4 a0 = make_float4(0.f, 0.f, 0.f, 0.f), a1 = a0;
    int e = s + eg;
    int i0 = 0, i1 = 0, i2 = 0, i3 = 0, i4 = 0, i5 = 0, i6 = 0, i7 = 0;
    bool have = (e + 56 < epe);
    if (have) {
        i0 = csr_row[e];      i1 = csr_row[e + 8];
        i2 = csr_row[e + 16]; i3 = csr_row[e + 24];
        i4 = csr_row[e + 32]; i5 = csr_row[e + 40];
        i6 = csr_row[e + 48]; i7 = csr_row[e + 56];
    }
    while (have) {
        int en = e + 64;
        bool hn = (en + 56 < epe);
        int j0 = 0, j1 = 0, j2 = 0, j3 = 0, j4 = 0, j5 = 0, j6 = 0, j7 = 0;
        if (hn) {                                // prefetch next iteration's indices
            j0 = csr_row[en];      j1 = csr_row[en + 8];
            j2 = csr_row[en + 16]; j3 = csr_row[en + 24];
            j4 = csr_row[en + 32]; j5 = csr_row[en + 40];
            j6 = csr_row[en + 48]; j7 = csr_row[en + 56];
        }
        uint4 v0 = h8[((size_t)i0 << 1) + q];
        uint4 v1 = h8[((size_t)i1 << 1) + q];
        uint4 v2 = h8[((size_t)i2 << 1) + q];
        uint4 v3 = h8[((size_t)i3 << 1) + q];
        uint4 v4 = h8[((size_t)i4 << 1) + q];
        uint4 v5 = h8[((size_t)i5 << 1) + q];
        uint4 v6 = h8[((size_t)i6 << 1) + q];
        uint4 v7 = h8[((size_t)i7 << 1) + q];
        accU(a0, a1, v0); accU(a0, a1, v1); accU(a0, a1, v2); accU(a0, a1, v3);
        accU(a0, a1, v4); accU(a0, a1, v5); accU(a0, a1, v6); accU(a0, a1, v7);
        i0 = j0; i1 = j1; i2 = j2; i3 = j3; i4 = j4; i5 = j5; i6 = j6; i7 = j7;
        e = en; have = hn;
    }
    for (; e + 8 < epe; e += 16) {
        int k0 = csr_row[e]; int k1 = csr_row[e + 8];
        uint4 v0 = h8[((size_t)k0 << 1) + q];
        uint4 v1 = h8[((size_t)k1 << 1) + q];
        accU(a0, a1, v0); accU(a0, a1, v1);
    }
    if (e < epe) {
        uint4 v0 = h8[((size_t)csr_row[e] << 1) + q];
        accU(a0, a1, v0);
    }
#define RED4(off) { float4 t0_ = shfl_down4(a0, off); float4 t1_ = shfl_down4(a1, off); \
                    a0.x += t0_.x; a0.y += t0_.y; a0.z += t0_.z; a0.w += t0_.w; \
                    a1.x += t1_.x; a1.y += t1_.y; a1.z += t1_.z; a1.w += t1_.w; }
    RED4(8) RED4(4) RED4(2)
#undef RED4
    float d = (c < N) ? dinv[c] : 0.f;
    float4 o0 = make_float4(0.f, 0.f, 0.f, 0.f), o1 = o0;
    if (sub < 2 && c < N) {
        uint4 su = h8[((size_t)c << 1) + q];   // self record half
        float2 s0 = __half22float2(*(const __half2*)&su.x);
        float2 s1 = __half22float2(*(const __half2*)&su.y);
        float2 s2 = __half22float2(*(const __half2*)&su.z);
        float2 s3 = __half22float2(*(const __half2*)&su.w);
        o0.x = d * (a0.x + s0.x); o0.y = d * (a0.y + s0.y);
        o0.z = d * (a0.z + s1.x); o0.w = d * (a0.w + s1.y);
        o1.x = d * (a1.x + s2.x); o1.y = d * (a1.y + s2.y);
        o1.z = d * (a1.z + s3.x); o1.w = d * (a1.w + s3.y);
        // bias + relu
        int bb = q * 8;
        o0.x = fmaxf(o0.x + bs[bb + 0], 0.f); o0.y = fmaxf(o0.y + bs[bb + 1], 0.f);
        o0.z = fmaxf(o0.z + bs[bb + 2], 0.f); o0.w = fmaxf(o0.w + bs[bb + 3], 0.f);
        o1.x = fmaxf(o1.x + bs[bb + 4], 0.f); o1.y = fmaxf(o1.y + bs[bb + 5], 0.f);
        o1.z = fmaxf(o1.z + bs[bb + 6], 0.f); o1.w = fmaxf(o1.w + bs[bb + 7], 0.f);
    }
    // broadcast the relu'd 16-vector to all 16 lanes of the node group
    int base = lane & ~15;
    float va[8], vb[8];
    va[0] = __shfl(o0.x, base, 64); va[1] = __shfl(o0.y, base, 64);
    va[2] = __shfl(o0.z, base, 64); va[3] = __shfl(o0.w, base, 64);
    va[4] = __shfl(o1.x, base, 64); va[5] = __shfl(o1.y, base, 64);
    va[6] = __shfl(o1.z, base, 64); va[7] = __shfl(o1.w, base, 64);
    vb[0] = __shfl(o0.x, base + 1, 64); vb[1] = __shfl(o0.y, base + 1, 64);
    vb[2] = __shfl(o0.z, base + 1, 64); vb[3] = __shfl(o0.w, base + 1, 64);
    vb[4] = __shfl(o1.x, base + 1, 64); vb[5] = __shfl(o1.y, base + 1, 64);
    vb[6] = __shfl(o1.z, base + 1, 64); vb[7] = __shfl(o1.w, base + 1, 64);
    if (FUSE == 1) {
        float acc = 0.f;
#pragma unroll
        for (int k = 0; k < 8; ++k) acc += va[k] * Wl[k * 16 + sub];
#pragma unroll
        for (int k = 0; k < 8; ++k) acc += vb[k] * Wl[(8 + k) * 16 + sub];
        if (c < N) hsout[(size_t)c * 16 + sub] = __float2half(acc * d);
    } else if (FUSE == 2) {
        int nl = (tid >> 4);                   // node index within block [0,16)
#pragma unroll
        for (int j = 0; j < 8; ++j) {
            int f = sub + 16 * j;
            float acc = bcs[f];
#pragma unroll
            for (int k = 0; k < 8; ++k)  acc += va[k] * Wl[k * DD + f];
#pragma unroll
            for (int k = 0; k < 7; ++k)  acc += vb[k] * Wl[(8 + k) * DD + f];
            sout[nl * DD + f] = acc;
        }
        __syncthreads();
        int n0 = blockIdx.x * 16;
        const float4* sv = (const float4*)sout;
#pragma unroll
        for (int r = 0; r < 2; ++r) {
            int idx = tid + 256 * r;           // 512 float4 = 16 nodes x 128 f
            int node = idx >> 5, rem = idx & 31;
            if (n0 + node < N)
                ((float4*)outF)[((size_t)(n0 + node) * DD >> 2) + rem] = sv[idx];
        }
    }
}

// ---------------- launch ----------------

extern "C" void kernel_launch(void* const* d_in, const int* in_sizes, int n_in,
                              void* d_out, int out_size, void* d_ws, size_t ws_size,
                              hipStream_t stream) {
    const float* x  = (const float*)d_in[0];
    const int*   ei = (const int*)d_in[1];
    const float* W1 = (const float*)d_in[2];
    const float* b1 = (const float*)d_in[3];
    const float* W2 = (const float*)d_in[4];
    const float* b2 = (const float*)d_in[5];
    const float* W3 = (const float*)d_in[6];
    const float* b3 = (const float*)d_in[7];
    const float* Wc = (const float*)d_in[8];
    const float* bc = (const float*)d_in[9];
    float* out = (float*)d_out;

    int N = in_sizes[0] / DD;   // 100000
    int E = in_sizes[1] / 2;    // 6400000
    const int* row = ei;        // edge_index[0] = source
    const int* col = ei + E;    // edge_index[1] = target

    char* ws = (char*)d_ws;
    size_t off = 0;
    auto alloc = [&](size_t bytes) {
        void* p = ws + off;
        off += (bytes + 255) & ~(size_t)255;
        return p;
    };
    float*    dinv     = (float*)   alloc((size_t)N * 4);
    int*      rowstart = (int*)     alloc((size_t)N * 4);
    int*      rowend   = (int*)     alloc((size_t)N * 4);
    int*      gcur     = (int*)     alloc((size_t)NBUCK * 4);
    int*      csr_row  = (int*)     alloc((size_t)NBUCK * CAP * 4 + 256); // 28.8 MB
    unsigned* tmp      = (unsigned*)alloc((size_t)NBUCK * CAP * 4);       // 28.8 MB
    (void)n_in; (void)out_size;

    // hs double-buffer: separate region if workspace allows (required for the
    // fused partB+gemm1 path: hs must not alias tmp while other blocks read tmp).
    size_t hsBytes = (size_t)N * 32;   // 3.2 MB each
    bool roomy = ws_size >= off + 2 * hsBytes + 4096;
    __half *hsA, *hsB;
    if (roomy) {
        hsA = (__half*)alloc(hsBytes);
        hsB = (__half*)alloc(hsBytes);
    } else {
        hsA = (__half*)tmp;                              // tmp dead after partB
        hsB = (__half*)((char*)tmp + hsBytes);
    }

    int eblocks = (E + CHUNK - 1) / CHUNK;             // 1563

    // CSR build: fixed-capacity regions end-to-end (no counting pass, no scanC).
    init_gcur<<<1, 512, 0, stream>>>(gcur);
    partA<<<eblocks, ABLK, 0, stream>>>(row, col, gcur, tmp, E);
    if (roomy) {
        partB<1><<<NBUCK, 1024, 0, stream>>>(gcur, tmp, rowstart, rowend, dinv,
                                             csr_row, x, W1, hsA, N);
    } else {
        partB<0><<<NBUCK, 1024, 0, stream>>>(gcur, tmp, rowstart, rowend, dinv,
                                             csr_row, x, W1, hsA, N);
        gemm1_kernel<<<(N + 15) / 16, 256, 0, stream>>>(x, W1, dinv, hsA);
    }

    int aggblocks = (N + 15) / 16;                     // 4 nodes/wave x 4 waves/block

    // aggregate 1 + fused layer-2 GEMM
    aggregate_kernel<1><<<aggblocks, 256, 0, stream>>>(rowstart, rowend, csr_row, dinv, hsA,
                                                       b1, W2, nullptr, hsB, nullptr, N);
    // aggregate 2 + fused layer-3 GEMM
    aggregate_kernel<1><<<aggblocks, 256, 0, stream>>>(rowstart, rowend, csr_row, dinv, hsB,
                                                       b2, W3, nullptr, hsA, nullptr, N);
    // aggregate 3 + fused output GEMM (writes out directly)
    aggregate_kernel<2><<<aggblocks, 256, 0, stream>>>(rowstart, rowend, csr_row, dinv, hsA,
                                                       b3, Wc, bc, nullptr, out, N);
}